// Round 7
// baseline (459.841 us; speedup 1.0000x reference)
//
#include <hip/hip_runtime.h>
#include <hip/hip_bf16.h>
#include <stdint.h>

typedef __attribute__((ext_vector_type(8))) short short8;
typedef __attribute__((ext_vector_type(4))) short short4v;
typedef __attribute__((ext_vector_type(4))) float floatx4;

#define B_   16
#define N_   1024
#define C_   768
#define H_   12
#define D_   64
#define K_   768
// (1/sqrt(64)) * log2(e): folds softmax scale AND natural->base2 exp into Q
#define QSCALE 0.18033688011112042f

__device__ __forceinline__ short f2bf(float f) {
    __hip_bfloat16 h = __float2bfloat16(f);
    short s; __builtin_memcpy(&s, &h, 2); return s;
}
// packed 2xf32 -> 2xbf16 (v_cvt_pk_bf16_f32 on gfx950)
__device__ __forceinline__ unsigned pk2bf(float a, float b) {
    __hip_bfloat162 h = __float22bfloat162_rn(make_float2(a, b));
    unsigned u; __builtin_memcpy(&u, &h, 4); return u;
}

// async global->LDS DMA, 16 B per lane; LDS dest = wave-uniform base + lane*16
__device__ __forceinline__ void gl_lds16(const void* g, void* l) {
    __builtin_amdgcn_global_load_lds(
        (const __attribute__((address_space(1))) unsigned int*)g,
        (__attribute__((address_space(3))) unsigned int*)l, 16, 0, 0);
}

// ---------------------------------------------------------------------------
// fused fp32->bf16 for x, w_qkv, w_proj (ranges are 256-block aligned)
// ---------------------------------------------------------------------------
#define N8_X  1572864   // (16*1024*768)/8
#define N8_WQ 221184    // (2304*768)/8
#define N8_WP 73728     // (768*768)/8
__global__ void cvt_all(const float* __restrict__ x, const float* __restrict__ wq,
                        const float* __restrict__ wp, short* __restrict__ xb,
                        short* __restrict__ wqb, short* __restrict__ wpb)
{
    long i = (long)blockIdx.x * 256 + threadIdx.x;   // 8-elem units
    const float* src; short* dst;
    if (i < N8_X)              { src = x;  dst = xb;  }
    else if (i < N8_X + N8_WQ) { src = wq; dst = wqb; i -= N8_X; }
    else                       { src = wp; dst = wpb; i -= (long)N8_X + N8_WQ; }
    const float4* p = (const float4*)src + 2 * i;
    const float4 u = p[0], v = p[1];
    short8 r;
    r[0] = f2bf(u.x); r[1] = f2bf(u.y); r[2] = f2bf(u.z); r[3] = f2bf(u.w);
    r[4] = f2bf(v.x); r[5] = f2bf(v.y); r[6] = f2bf(v.z); r[7] = f2bf(v.w);
    *((short8*)dst + i) = r;
}

// ---------------------------------------------------------------------------
// GEMM  C[M,N] = A[M,K] * B[N,K]^T  (bf16, K-major, 128x128 tile, BK=32,
// global_load_lds staging — m97 structure).
// MODE 0: QKV epilogue -> q_ws [bh,n,d] (scaled), k_ws [bh,n,d],
//         v_ws [bh,d,n_virt] (transposed + k_virt-permuted per 64-chunk)
// MODE 1: proj epilogue -> +bias, fp32 out
// ---------------------------------------------------------------------------
template<int MODE>
__global__ __launch_bounds__(256, 3)
void gemm_bt(const short* __restrict__ A, const short* __restrict__ Bm,
             const float* __restrict__ bias,
             short* __restrict__ q_ws, short* __restrict__ k_ws,
             short* __restrict__ v_ws, float* __restrict__ outp)
{
    __shared__ short Alds[128 * 32];
    __shared__ short Blds[128 * 32];
    const int tid  = threadIdx.x;
    const int wave = tid >> 6, lane = tid & 63;
    const int cl   = lane & 15, quad = lane >> 4;
    const int bm = blockIdx.x, bn = blockIdx.y;
    const int wm = (wave >> 1) * 64, wn = (wave & 1) * 64;

    const short* Ag = A  + (long)bm * 128 * K_ + (long)(tid >> 2) * K_ + (tid & 3) * 8;
    const short* Bg = Bm + (long)bn * 128 * K_ + (long)(tid >> 2) * K_ + (tid & 3) * 8;
    short* la = Alds + (tid & 0xC0) * 8;   // wave-uniform base
    short* lb = Blds + (tid & 0xC0) * 8;

    const floatx4 fzero = {0.f, 0.f, 0.f, 0.f};
    floatx4 acc[4][4];
    #pragma unroll
    for (int i = 0; i < 4; i++)
        #pragma unroll
        for (int j = 0; j < 4; j++) acc[i][j] = fzero;

    for (int kt = 0; kt < K_; kt += 32) {
        __syncthreads();                    // previous iter's readers done
        gl_lds16(Ag + kt,            la);
        gl_lds16(Ag + kt + 64 * K_,  la + 2048);
        gl_lds16(Bg + kt,            lb);
        gl_lds16(Bg + kt + 64 * K_,  lb + 2048);
        __syncthreads();                    // drains vmcnt (DMA complete)

        short8 af[4], bf[4];
        #pragma unroll
        for (int i = 0; i < 4; i++)
            af[i] = *(const short8*)(Alds + (wm + i * 16 + cl) * 32 + quad * 8);
        #pragma unroll
        for (int j = 0; j < 4; j++)
            bf[j] = *(const short8*)(Blds + (wn + j * 16 + cl) * 32 + quad * 8);
        #pragma unroll
        for (int i = 0; i < 4; i++)
            #pragma unroll
            for (int j = 0; j < 4; j++)
                acc[i][j] = __builtin_amdgcn_mfma_f32_16x16x32_bf16(af[i], bf[j], acc[i][j], 0, 0, 0);
    }

    // epilogue.  C/D layout: row(m) = quad*4 + reg, col(n) = cl  [m89/m91]
    #pragma unroll
    for (int i = 0; i < 4; i++) {
        const int gm0 = bm * 128 + wm + i * 16 + quad * 4;
        #pragma unroll
        for (int j = 0; j < 4; j++) {
            const int gn = bn * 128 + wn + j * 16 + cl;
            if (MODE == 0) {
                const int t   = bn / 6;          // 0=Q,1=K,2=V (block-uniform)
                const int rem = gn - t * 768;
                const int h   = rem >> 6, d = rem & 63;
                const int b   = gm0 >> 10;
                const int n0  = gm0 & 1023;
                const int bh  = b * H_ + h;
                if (t == 2) {
                    // k_virt permute within each 64-token chunk:
                    // virt = (n & ~63) | ((n&15)*4 + ((n>>4)&3))
                    #pragma unroll
                    for (int r = 0; r < 4; r++) {
                        const int n = n0 + r, w = n & 63;
                        const int vn = (n & ~63) | (((w & 15) << 2) | (w >> 4));
                        v_ws[(((long)(bh * D_ + d)) << 10) + vn] = f2bf(acc[i][j][r]);
                    }
                } else {
                    short* dst = (t == 0) ? q_ws : k_ws;
                    const float sc = (t == 0) ? QSCALE : 1.0f;
                    #pragma unroll
                    for (int r = 0; r < 4; r++)
                        dst[((long)bh * N_ + (n0 + r)) * D_ + d] = f2bf(acc[i][j][r] * sc);
                }
            } else {
                const float bv = bias[gn];
                #pragma unroll
                for (int r = 0; r < 4; r++)
                    outp[(long)(gm0 + r) * C_ + gn] = acc[i][j][r] + bv;   // fp32 out
            }
        }
    }
}

// ---------------------------------------------------------------------------
// Flash attention v2: one block = one (b,h) x 128 Q-rows, 64-key chunks.
// LDS 25.6 KB -> 6 blocks/CU. Unpadded 64x64 K/V tiles with XOR-segment
// swizzle (seg' = seg ^ (row&7)) -> conflict-free b128 fragment reads.
// V arrives pre-permuted in k_virt order (virt = cl*4 + nt), so each lane's
// 4 P-values per row are contiguous: packed cvt + one 8B write per row.
// ---------------------------------------------------------------------------
__global__ __launch_bounds__(256, 6)
void attn_fused(const short* __restrict__ q_ws, const short* __restrict__ k_ws,
                const short* __restrict__ v_ws, short* __restrict__ o_ws)
{
    __shared__ short Klds[64 * 64];       // [key][d], XOR-swizzled segs
    __shared__ short Vlds[64 * 64];       // [d][k_virt], XOR-swizzled segs
    __shared__ short Plds[4][16 * 72];    // per-wave [qrow][k_virt], pad 64->72

    const int tid  = threadIdx.x;
    const int wave = tid >> 6, lane = tid & 63;
    const int cl   = lane & 15, quad = lane >> 4;

    // XCD swizzle: each XCD owns 24 bh, qt-minor -> ~12 resident bh in its L2
    const int linear = blockIdx.y * 8 + blockIdx.x;   // gridDim = (8, 192)
    const int xcd = linear & 7, slot = linear >> 3;
    const int bh  = xcd * 24 + (slot >> 3);
    const int qt  = slot & 7;

    const long base = (long)bh * (N_ * D_);
    const int  qr0  = qt * 128 + wave * 32 + cl;

    short8 qf[2][2];
    #pragma unroll
    for (int mt = 0; mt < 2; mt++) {
        qf[mt][0] = *(const short8*)(q_ws + base + (long)(qr0 + mt * 16) * D_ + quad * 8);
        qf[mt][1] = *(const short8*)(q_ws + base + (long)(qr0 + mt * 16) * D_ + 32 + quad * 8);
    }

    const floatx4 fzero = {0.f, 0.f, 0.f, 0.f};
    float m_r[2][4], l_r[2][4];
    floatx4 o_acc[2][4];
    #pragma unroll
    for (int mt = 0; mt < 2; mt++)
        #pragma unroll
        for (int r = 0; r < 4; r++) {
            m_r[mt][r] = -1e30f; l_r[mt][r] = 0.f; o_acc[mt][r] = fzero;
        }

    const int srow = tid >> 2;          // 0..63: key row (K) / d row (V)
    const int sg0  = (tid & 3) * 2;     // first of two 8-short segments
    const int xw   = srow & 7;          // write-side XOR
    const int xr   = cl & 7;            // read-side XOR (row & 7 == cl & 7)
    short* pl = &Plds[wave][0];

    for (int kc = 0; kc < N_; kc += 64) {
        short8 k0 = *(const short8*)(k_ws + base + (long)(kc + srow) * D_ + sg0 * 8);
        short8 k1 = *(const short8*)(k_ws + base + (long)(kc + srow) * D_ + sg0 * 8 + 8);
        short8 v0 = *(const short8*)(v_ws + base + (long)srow * N_ + kc + sg0 * 8);
        short8 v1 = *(const short8*)(v_ws + base + (long)srow * N_ + kc + sg0 * 8 + 8);
        __syncthreads();
        *(short8*)(Klds + srow * 64 + ((sg0    ) ^ xw) * 8) = k0;
        *(short8*)(Klds + srow * 64 + ((sg0 + 1) ^ xw) * 8) = k1;
        *(short8*)(Vlds + srow * 64 + ((sg0    ) ^ xw) * 8) = v0;
        *(short8*)(Vlds + srow * 64 + ((sg0 + 1) ^ xw) * 8) = v1;
        __syncthreads();

        #pragma unroll
        for (int mt = 0; mt < 2; mt++) {
            // S = Q*K^T: lane cl holds key k_phys = nt*16+cl
            floatx4 s[4];
            #pragma unroll
            for (int nt = 0; nt < 4; nt++) {
                const short* kr = Klds + (nt * 16 + cl) * 64;
                short8 kf0 = *(const short8*)(kr + ((quad    ) ^ xr) * 8);
                short8 kf1 = *(const short8*)(kr + ((quad + 4) ^ xr) * 8);
                floatx4 t4 = fzero;
                t4 = __builtin_amdgcn_mfma_f32_16x16x32_bf16(qf[mt][0], kf0, t4, 0, 0, 0);
                t4 = __builtin_amdgcn_mfma_f32_16x16x32_bf16(qf[mt][1], kf1, t4, 0, 0, 0);
                s[nt] = t4;
            }

            // online softmax; rows = quad*4 + r
            float alpha[4];
            #pragma unroll
            for (int r = 0; r < 4; r++) {
                float v = fmaxf(fmaxf(s[0][r], s[1][r]), fmaxf(s[2][r], s[3][r]));
                v = fmaxf(v, __shfl_xor(v, 1));
                v = fmaxf(v, __shfl_xor(v, 2));
                v = fmaxf(v, __shfl_xor(v, 4));
                v = fmaxf(v, __shfl_xor(v, 8));
                const float mn = fmaxf(m_r[mt][r], v);
                alpha[r] = __builtin_amdgcn_exp2f(m_r[mt][r] - mn);
                m_r[mt][r] = mn;
                l_r[mt][r] *= alpha[r];
            }
            // P: lane's 4 values per row at k_virt = cl*4 + nt -> contiguous 8B
            #pragma unroll
            for (int r = 0; r < 4; r++) {
                float p0 = __builtin_amdgcn_exp2f(s[0][r] - m_r[mt][r]);
                float p1 = __builtin_amdgcn_exp2f(s[1][r] - m_r[mt][r]);
                float p2 = __builtin_amdgcn_exp2f(s[2][r] - m_r[mt][r]);
                float p3 = __builtin_amdgcn_exp2f(s[3][r] - m_r[mt][r]);
                l_r[mt][r] += (p0 + p1) + (p2 + p3);
                uint2 pk = { pk2bf(p0, p1), pk2bf(p2, p3) };
                *(uint2*)(pl + (quad * 4 + r) * 72 + cl * 4) = pk;
            }
            #pragma unroll
            for (int dt = 0; dt < 4; dt++) {
                o_acc[mt][dt][0] *= alpha[0]; o_acc[mt][dt][1] *= alpha[1];
                o_acc[mt][dt][2] *= alpha[2]; o_acc[mt][dt][3] *= alpha[3];
            }
            asm volatile("" ::: "memory");   // order P writes before P reads

            // O += P*V over k_virt: A=P [m=cl][k], B=V [n=d][k]
            #pragma unroll
            for (int ks = 0; ks < 2; ks++) {
                short8 pf = *(const short8*)(pl + cl * 72 + ks * 32 + quad * 8);
                #pragma unroll
                for (int dt = 0; dt < 4; dt++) {
                    const short* vr = Vlds + (dt * 16 + cl) * 64;
                    short8 vf = *(const short8*)(vr + ((ks * 4 + quad) ^ xr) * 8);
                    o_acc[mt][dt] = __builtin_amdgcn_mfma_f32_16x16x32_bf16(pf, vf, o_acc[mt][dt], 0, 0, 0);
                }
            }
            asm volatile("" ::: "memory");   // P reads done before next mt's writes
        }
    }

    // finalize: reduce l across the quad's 16 lanes, normalize, store [b,n,c]
    const int b = bh / H_, h = bh - b * H_;
    #pragma unroll
    for (int mt = 0; mt < 2; mt++) {
        #pragma unroll
        for (int r = 0; r < 4; r++) {
            float v = l_r[mt][r];
            v += __shfl_xor(v, 1); v += __shfl_xor(v, 2);
            v += __shfl_xor(v, 4); v += __shfl_xor(v, 8);
            l_r[mt][r] = 1.0f / v;
        }
        const int nrow = qt * 128 + wave * 32 + mt * 16 + quad * 4;
        #pragma unroll
        for (int dt = 0; dt < 4; dt++) {
            const int c = h * D_ + dt * 16 + cl;
            #pragma unroll
            for (int r = 0; r < 4; r++)
                o_ws[((long)(b * N_ + nrow + r)) * C_ + c] = f2bf(o_acc[mt][dt][r] * l_r[mt][r]);
        }
    }
}

extern "C" void kernel_launch(void* const* d_in, const int* in_sizes, int n_in,
                              void* d_out, int out_size, void* d_ws, size_t ws_size,
                              hipStream_t stream)
{
    const float* x      = (const float*)d_in[0];
    const float* w_qkv  = (const float*)d_in[1];
    const float* w_proj = (const float*)d_in[2];
    const float* b_proj = (const float*)d_in[3];
    float* out = (float*)d_out;

    const long SZ = (long)B_ * N_ * C_;
    short* q_ws   = (short*)d_ws;                  // [bh, n, d] (pre-scaled)
    short* k_ws   = q_ws + SZ;                     // [bh, n, d]
    short* v_ws   = k_ws + SZ;                     // [bh, d, n_virt]
    short* x_bf   = v_ws + SZ;                     // x as bf16; reused as o_ws
    short* o_ws   = x_bf;                          // alias: x dead after QKV GEMM
    short* wqkv_bf  = x_bf + SZ;
    short* wproj_bf = wqkv_bf + (long)3 * C_ * C_;

    cvt_all<<<dim3(7296), 256, 0, stream>>>(x, w_qkv, w_proj, x_bf, wqkv_bf, wproj_bf);
    gemm_bt<0><<<dim3(128, 18), 256, 0, stream>>>(x_bf, wqkv_bf, nullptr, q_ws, k_ws, v_ws, nullptr);
    attn_fused<<<dim3(8, 192), 256, 0, stream>>>(q_ws, k_ws, v_ws, o_ws);
    gemm_bt<1><<<dim3(128, 6), 256, 0, stream>>>(o_ws, wproj_bf, b_proj, nullptr, nullptr, nullptr, out);
}

// Round 8
// 337.176 us; speedup vs baseline: 1.3638x; 1.3638x over previous
//
#include <hip/hip_runtime.h>
#include <hip/hip_bf16.h>
#include <stdint.h>

typedef __attribute__((ext_vector_type(8))) short short8;
typedef __attribute__((ext_vector_type(4))) short short4v;
typedef __attribute__((ext_vector_type(4))) float floatx4;

#define B_   16
#define N_   1024
#define C_   768
#define H_   12
#define D_   64
#define K_   768
// (1/sqrt(64)) * log2(e): folds softmax scale AND natural->base2 exp into Q
#define QSCALE 0.18033688011112042f

__device__ __forceinline__ short f2bf(float f) {
    __hip_bfloat16 h = __float2bfloat16(f);
    short s; __builtin_memcpy(&s, &h, 2); return s;
}
// packed 2xf32 -> 2xbf16 (v_cvt_pk_bf16_f32 on gfx950)
__device__ __forceinline__ unsigned pk2bf(float a, float b) {
    __hip_bfloat162 h = __float22bfloat162_rn(make_float2(a, b));
    unsigned u; __builtin_memcpy(&u, &h, 4); return u;
}

// async global->LDS DMA, 16 B per lane; LDS dest = wave-uniform base + lane*16
__device__ __forceinline__ void gl_lds16(const void* g, void* l) {
    __builtin_amdgcn_global_load_lds(
        (const __attribute__((address_space(1))) unsigned int*)g,
        (__attribute__((address_space(3))) unsigned int*)l, 16, 0, 0);
}

// ---------------------------------------------------------------------------
// fused fp32->bf16 for x, w_qkv, w_proj (ranges are 256-block aligned)
// ---------------------------------------------------------------------------
#define N8_X  1572864   // (16*1024*768)/8
#define N8_WQ 221184    // (2304*768)/8
#define N8_WP 73728     // (768*768)/8
__global__ void cvt_all(const float* __restrict__ x, const float* __restrict__ wq,
                        const float* __restrict__ wp, short* __restrict__ xb,
                        short* __restrict__ wqb, short* __restrict__ wpb)
{
    long i = (long)blockIdx.x * 256 + threadIdx.x;   // 8-elem units
    const float* src; short* dst;
    if (i < N8_X)              { src = x;  dst = xb;  }
    else if (i < N8_X + N8_WQ) { src = wq; dst = wqb; i -= N8_X; }
    else                       { src = wp; dst = wpb; i -= (long)N8_X + N8_WQ; }
    const float4* p = (const float4*)src + 2 * i;
    const float4 u = p[0], v = p[1];
    short8 r;
    r[0] = f2bf(u.x); r[1] = f2bf(u.y); r[2] = f2bf(u.z); r[3] = f2bf(u.w);
    r[4] = f2bf(v.x); r[5] = f2bf(v.y); r[6] = f2bf(v.z); r[7] = f2bf(v.w);
    *((short8*)dst + i) = r;
}

// ---------------------------------------------------------------------------
// GEMM  C[M,N] = A[M,K] * B[N,K]^T  (bf16, K-major, 128x128 tile, BK=32,
// global_load_lds staging — m97 structure).
// MODE 0: QKV epilogue -> q_ws [bh,n,d] (scaled), k_ws [bh,n,d], v_ws [bh,d,n]
// MODE 1: proj epilogue -> +bias, fp32 out
// ---------------------------------------------------------------------------
template<int MODE>
__global__ __launch_bounds__(256, 3)
void gemm_bt(const short* __restrict__ A, const short* __restrict__ Bm,
             const float* __restrict__ bias,
             short* __restrict__ q_ws, short* __restrict__ k_ws,
             short* __restrict__ v_ws, float* __restrict__ outp)
{
    __shared__ short Alds[128 * 32];
    __shared__ short Blds[128 * 32];
    const int tid  = threadIdx.x;
    const int wave = tid >> 6, lane = tid & 63;
    const int cl   = lane & 15, quad = lane >> 4;
    const int bm = blockIdx.x, bn = blockIdx.y;
    const int wm = (wave >> 1) * 64, wn = (wave & 1) * 64;

    const short* Ag = A  + (long)bm * 128 * K_ + (long)(tid >> 2) * K_ + (tid & 3) * 8;
    const short* Bg = Bm + (long)bn * 128 * K_ + (long)(tid >> 2) * K_ + (tid & 3) * 8;
    short* la = Alds + (tid & 0xC0) * 8;   // wave-uniform base
    short* lb = Blds + (tid & 0xC0) * 8;

    const floatx4 fzero = {0.f, 0.f, 0.f, 0.f};
    floatx4 acc[4][4];
    #pragma unroll
    for (int i = 0; i < 4; i++)
        #pragma unroll
        for (int j = 0; j < 4; j++) acc[i][j] = fzero;

    for (int kt = 0; kt < K_; kt += 32) {
        __syncthreads();                    // previous iter's readers done
        gl_lds16(Ag + kt,            la);
        gl_lds16(Ag + kt + 64 * K_,  la + 2048);
        gl_lds16(Bg + kt,            lb);
        gl_lds16(Bg + kt + 64 * K_,  lb + 2048);
        __syncthreads();                    // drains vmcnt (DMA complete)

        short8 af[4], bf[4];
        #pragma unroll
        for (int i = 0; i < 4; i++)
            af[i] = *(const short8*)(Alds + (wm + i * 16 + cl) * 32 + quad * 8);
        #pragma unroll
        for (int j = 0; j < 4; j++)
            bf[j] = *(const short8*)(Blds + (wn + j * 16 + cl) * 32 + quad * 8);
        #pragma unroll
        for (int i = 0; i < 4; i++)
            #pragma unroll
            for (int j = 0; j < 4; j++)
                acc[i][j] = __builtin_amdgcn_mfma_f32_16x16x32_bf16(af[i], bf[j], acc[i][j], 0, 0, 0);
    }

    // epilogue.  C/D layout: row(m) = quad*4 + reg, col(n) = cl  [m89/m91]
    #pragma unroll
    for (int i = 0; i < 4; i++) {
        const int gm0 = bm * 128 + wm + i * 16 + quad * 4;
        #pragma unroll
        for (int j = 0; j < 4; j++) {
            const int gn = bn * 128 + wn + j * 16 + cl;
            if (MODE == 0) {
                const int t   = bn / 6;          // 0=Q,1=K,2=V (block-uniform)
                const int rem = gn - t * 768;
                const int h   = rem >> 6, d = rem & 63;
                const int b   = gm0 >> 10;
                const int n0  = gm0 & 1023;
                const int bh  = b * H_ + h;
                if (t == 2) {
                    short4v pk;
                    #pragma unroll
                    for (int r = 0; r < 4; r++) pk[r] = f2bf(acc[i][j][r]);
                    *(short4v*)(v_ws + (((long)(bh * D_ + d)) << 10) + n0) = pk;   // [bh,d,n]
                } else {
                    short* dst = (t == 0) ? q_ws : k_ws;
                    const float sc = (t == 0) ? QSCALE : 1.0f;
                    #pragma unroll
                    for (int r = 0; r < 4; r++)
                        dst[((long)bh * N_ + (n0 + r)) * D_ + d] = f2bf(acc[i][j][r] * sc);
                }
            } else {
                const float bv = bias[gn];
                #pragma unroll
                for (int r = 0; r < 4; r++)
                    outp[(long)(gm0 + r) * C_ + gn] = acc[i][j][r] + bv;   // fp32 out
            }
        }
    }
}

// ---------------------------------------------------------------------------
// Flash attention v3: one block = one (b,h) x 128 Q-rows, 64-key chunks.
// 64x64 K/V tiles, XOR-segment swizzle (conflict-free b128), natural V [d][n].
// KEY TRICK: QK^T tile nt maps S-column cl to key cl*4+nt (a free LDS-address
// permutation of K rows) -> each lane's 4 P-values are CONTIGUOUS keys ->
// packed cvt + one 8B LDS write per row; V needs no permutation at all.
// LDS padded to ~49 KB to cap at 3 blocks/CU: resident window per XCD =
// 12 bh = 3 MB KV <= 4 MB L2 (round 7 showed 6 blocks/CU -> 24 bh -> thrash).
// ---------------------------------------------------------------------------
#define PSTRIDE (16 * 72 + 3072)   // per-wave P stride (pad caps occupancy at 3/CU)
__global__ __launch_bounds__(256, 3)
void attn_fused(const short* __restrict__ q_ws, const short* __restrict__ k_ws,
                const short* __restrict__ v_ws, short* __restrict__ o_ws)
{
    __shared__ short Klds[64 * 64];       // [key][d], XOR-swizzled segs
    __shared__ short Vlds[64 * 64];       // [d][key], XOR-swizzled segs
    __shared__ short Plds[4 * PSTRIDE];   // per-wave [qrow][key 0..63] pad 72

    const int tid  = threadIdx.x;
    const int wave = tid >> 6, lane = tid & 63;
    const int cl   = lane & 15, quad = lane >> 4;

    // XCD swizzle: each XCD owns 24 bh, qt-minor
    const int linear = blockIdx.y * 8 + blockIdx.x;   // gridDim = (8, 192)
    const int xcd = linear & 7, slot = linear >> 3;
    const int bh  = xcd * 24 + (slot >> 3);
    const int qt  = slot & 7;

    const long base = (long)bh * (N_ * D_);
    const int  qr0  = qt * 128 + wave * 32 + cl;

    short8 qf[2][2];
    #pragma unroll
    for (int mt = 0; mt < 2; mt++) {
        qf[mt][0] = *(const short8*)(q_ws + base + (long)(qr0 + mt * 16) * D_ + quad * 8);
        qf[mt][1] = *(const short8*)(q_ws + base + (long)(qr0 + mt * 16) * D_ + 32 + quad * 8);
    }

    const floatx4 fzero = {0.f, 0.f, 0.f, 0.f};
    float m_r[2][4], l_r[2][4];
    floatx4 o_acc[2][4];
    #pragma unroll
    for (int mt = 0; mt < 2; mt++)
        #pragma unroll
        for (int r = 0; r < 4; r++) {
            m_r[mt][r] = -1e30f; l_r[mt][r] = 0.f; o_acc[mt][r] = fzero;
        }

    const int srow = tid >> 2;          // 0..63: key row (K) / d row (V)
    const int sg0  = (tid & 3) * 2;     // first of two 8-short segments
    const int xw   = srow & 7;          // write-side XOR
    short* pl = &Plds[wave * PSTRIDE];

    for (int kc = 0; kc < N_; kc += 64) {
        short8 k0 = *(const short8*)(k_ws + base + (long)(kc + srow) * D_ + sg0 * 8);
        short8 k1 = *(const short8*)(k_ws + base + (long)(kc + srow) * D_ + sg0 * 8 + 8);
        short8 v0 = *(const short8*)(v_ws + base + (long)srow * N_ + kc + sg0 * 8);
        short8 v1 = *(const short8*)(v_ws + base + (long)srow * N_ + kc + sg0 * 8 + 8);
        __syncthreads();
        *(short8*)(Klds + srow * 64 + ((sg0    ) ^ xw) * 8) = k0;
        *(short8*)(Klds + srow * 64 + ((sg0 + 1) ^ xw) * 8) = k1;
        *(short8*)(Vlds + srow * 64 + ((sg0    ) ^ xw) * 8) = v0;
        *(short8*)(Vlds + srow * 64 + ((sg0 + 1) ^ xw) * 8) = v1;
        __syncthreads();

        #pragma unroll
        for (int mt = 0; mt < 2; mt++) {
            // S = Q*K^T; tile nt: S-col cl <-> key cl*4+nt (free permutation)
            floatx4 s[4];
            #pragma unroll
            for (int nt = 0; nt < 4; nt++) {
                const int krow = cl * 4 + nt;
                const int xr   = krow & 7;
                const short* kr = Klds + krow * 64;
                short8 kf0 = *(const short8*)(kr + ((quad    ) ^ xr) * 8);
                short8 kf1 = *(const short8*)(kr + ((quad + 4) ^ xr) * 8);
                floatx4 t4 = fzero;
                t4 = __builtin_amdgcn_mfma_f32_16x16x32_bf16(qf[mt][0], kf0, t4, 0, 0, 0);
                t4 = __builtin_amdgcn_mfma_f32_16x16x32_bf16(qf[mt][1], kf1, t4, 0, 0, 0);
                s[nt] = t4;
            }

            // online softmax; rows = quad*4 + r (max/sum are key-order-invariant)
            float alpha[4];
            #pragma unroll
            for (int r = 0; r < 4; r++) {
                float v = fmaxf(fmaxf(s[0][r], s[1][r]), fmaxf(s[2][r], s[3][r]));
                v = fmaxf(v, __shfl_xor(v, 1));
                v = fmaxf(v, __shfl_xor(v, 2));
                v = fmaxf(v, __shfl_xor(v, 4));
                v = fmaxf(v, __shfl_xor(v, 8));
                const float mn = fmaxf(m_r[mt][r], v);
                alpha[r] = __builtin_amdgcn_exp2f(m_r[mt][r] - mn);
                m_r[mt][r] = mn;
                l_r[mt][r] *= alpha[r];
            }
            // P: lane's 4 values per row are keys cl*4..cl*4+3 -> contiguous 8B
            #pragma unroll
            for (int r = 0; r < 4; r++) {
                float p0 = __builtin_amdgcn_exp2f(s[0][r] - m_r[mt][r]);
                float p1 = __builtin_amdgcn_exp2f(s[1][r] - m_r[mt][r]);
                float p2 = __builtin_amdgcn_exp2f(s[2][r] - m_r[mt][r]);
                float p3 = __builtin_amdgcn_exp2f(s[3][r] - m_r[mt][r]);
                l_r[mt][r] += (p0 + p1) + (p2 + p3);
                uint2 pk = { pk2bf(p0, p1), pk2bf(p2, p3) };
                *(uint2*)(pl + (quad * 4 + r) * 72 + cl * 4) = pk;
            }
            #pragma unroll
            for (int dt = 0; dt < 4; dt++) {
                o_acc[mt][dt][0] *= alpha[0]; o_acc[mt][dt][1] *= alpha[1];
                o_acc[mt][dt][2] *= alpha[2]; o_acc[mt][dt][3] *= alpha[3];
            }
            asm volatile("" ::: "memory");   // order P writes before P reads

            // O += P*V: A=P [m=cl][k=key], B=V [n=d][k=key] (natural order)
            #pragma unroll
            for (int ks = 0; ks < 2; ks++) {
                short8 pf = *(const short8*)(pl + cl * 72 + ks * 32 + quad * 8);
                #pragma unroll
                for (int dt = 0; dt < 4; dt++) {
                    const int vrow = dt * 16 + cl;
                    const int xr   = vrow & 7;
                    const short* vr = Vlds + vrow * 64;
                    short8 vf = *(const short8*)(vr + ((ks * 4 + quad) ^ xr) * 8);
                    o_acc[mt][dt] = __builtin_amdgcn_mfma_f32_16x16x32_bf16(pf, vf, o_acc[mt][dt], 0, 0, 0);
                }
            }
            asm volatile("" ::: "memory");   // P reads done before next mt's writes
        }
    }

    // finalize: reduce l across the quad's 16 lanes, normalize, store [b,n,c]
    const int b = bh / H_, h = bh - b * H_;
    #pragma unroll
    for (int mt = 0; mt < 2; mt++) {
        #pragma unroll
        for (int r = 0; r < 4; r++) {
            float v = l_r[mt][r];
            v += __shfl_xor(v, 1); v += __shfl_xor(v, 2);
            v += __shfl_xor(v, 4); v += __shfl_xor(v, 8);
            l_r[mt][r] = 1.0f / v;
        }
        const int nrow = qt * 128 + wave * 32 + mt * 16 + quad * 4;
        #pragma unroll
        for (int dt = 0; dt < 4; dt++) {
            const int c = h * D_ + dt * 16 + cl;
            #pragma unroll
            for (int r = 0; r < 4; r++)
                o_ws[((long)(b * N_ + nrow + r)) * C_ + c] = f2bf(o_acc[mt][dt][r] * l_r[mt][r]);
        }
    }
}

extern "C" void kernel_launch(void* const* d_in, const int* in_sizes, int n_in,
                              void* d_out, int out_size, void* d_ws, size_t ws_size,
                              hipStream_t stream)
{
    const float* x      = (const float*)d_in[0];
    const float* w_qkv  = (const float*)d_in[1];
    const float* w_proj = (const float*)d_in[2];
    const float* b_proj = (const float*)d_in[3];
    float* out = (float*)d_out;

    const long SZ = (long)B_ * N_ * C_;
    short* q_ws   = (short*)d_ws;                  // [bh, n, d] (pre-scaled)
    short* k_ws   = q_ws + SZ;                     // [bh, n, d]
    short* v_ws   = k_ws + SZ;                     // [bh, d, n]
    short* x_bf   = v_ws + SZ;                     // x as bf16; reused as o_ws
    short* o_ws   = x_bf;                          // alias: x dead after QKV GEMM
    short* wqkv_bf  = x_bf + SZ;
    short* wproj_bf = wqkv_bf + (long)3 * C_ * C_;

    cvt_all<<<dim3(7296), 256, 0, stream>>>(x, w_qkv, w_proj, x_bf, wqkv_bf, wproj_bf);
    gemm_bt<0><<<dim3(128, 18), 256, 0, stream>>>(x_bf, wqkv_bf, nullptr, q_ws, k_ws, v_ws, nullptr);
    attn_fused<<<dim3(8, 192), 256, 0, stream>>>(q_ws, k_ws, v_ws, o_ws);
    gemm_bt<1><<<dim3(128, 6), 256, 0, stream>>>(o_ws, wproj_bf, b_proj, nullptr, nullptr, nullptr, out);
}